// Round 7
// baseline (211.766 us; speedup 1.0000x reference)
//
#include <hip/hip_runtime.h>
#include <math.h>

#define NMODELS 64
#define HID     64
#define TS      32          // samples per tile
#define LSTR    68          // LDS row stride: 272B = 16B-aligned rows, conflict-free b128

// workspace layout (int32 indices)
#define WS_NT    0
#define WS_HIST  16
#define WS_CUR   96
#define WS_TILES 192        // 3 ints per tile
#define MAX_TILES 1088      // 32768/32 + 64 = 8 * 136
#define XCD_CHUNK 136
#define WS_SEL   4096
#define WS_PERM  36864

// output layout (float32 indices)
#define OUT_SEL  393216
#define OUT_LOG  425984
#define OUT_PROB 2523136

__global__ void k_init(int* __restrict__ wsi) {
  if (threadIdx.x < NMODELS) wsi[WS_HIST + threadIdx.x] = 0;
}

// routing + constant fills (logits=1, probs=1/64) in one pass
__global__ void k_route(const float* __restrict__ in, float* __restrict__ out,
                        int* __restrict__ wsi) {
  __shared__ int lh[NMODELS];
  int t = threadIdx.x;
  if (t < NMODELS) lh[t] = 0;
  __syncthreads();
  int b = blockIdx.x * 256 + t;          // 0..32767

  // constant fills: 2M floats per region = 16 float4 per thread, coalesced
  {
    float4 one = make_float4(1.f, 1.f, 1.f, 1.f);
    float4 pr  = make_float4(0.015625f, 0.015625f, 0.015625f, 0.015625f);
    float4* lg = reinterpret_cast<float4*>(out + OUT_LOG);
    float4* pb = reinterpret_cast<float4*>(out + OUT_PROB);
    #pragma unroll
    for (int k = 0; k < 16; ++k) {
      lg[k * 32768 + b] = one;
      pb[k * 32768 + b] = pr;
    }
  }

  float x = in[b * 6 + 0];
  float z = in[b * 6 + 2];
  const float TWO_PI = 6.283185307179586476925286766559f;
  // f64 atan2 rounded to f32 ~= correctly-rounded f32 atan2 (matches numpy);
  // remaining chain is IEEE-exact f32, bit-identical to the reference.
  float ang = (float)atan2((double)z, (double)x);
  float tt  = ang + TWO_PI;
  float m   = fmodf(tt, TWO_PI);
  float a   = m / TWO_PI * 64.0f;
  int e = (int)floorf(a);
  e = e < 0 ? 0 : (e > 63 ? 63 : e);
  out[OUT_SEL + b] = (float)e;
  wsi[WS_SEL + b]  = e;
  atomicAdd(&lh[e], 1);
  __syncthreads();
  if (t < NMODELS && lh[t] > 0) atomicAdd(&wsi[WS_HIST + t], lh[t]);
}

__global__ void k_prefix(int* __restrict__ wsi) {  // 1 block, 64 threads (one wave)
  int t = threadIdx.x;      // t = expert id
  int c = wsi[WS_HIST + t];
  int x = c;
  #pragma unroll
  for (int d = 1; d < 64; d <<= 1) {
    int y = __shfl_up(x, d, 64);
    if (t >= d) x += y;
  }
  int off = x - c;                 // exclusive prefix of counts
  wsi[WS_CUR + t] = off;           // scatter cursor starts at segment base
  int ntile_me = (c + TS - 1) >> 5;
  int tx = ntile_me;
  #pragma unroll
  for (int d = 1; d < 64; d <<= 1) {
    int y = __shfl_up(tx, d, 64);
    if (t >= d) tx += y;
  }
  int tbase = tx - ntile_me;
  for (int k = 0; k < ntile_me; ++k) {
    int rem = c - k * TS;
    wsi[WS_TILES + (tbase + k) * 3 + 0] = t;
    wsi[WS_TILES + (tbase + k) * 3 + 1] = off + k * TS;
    wsi[WS_TILES + (tbase + k) * 3 + 2] = rem < TS ? rem : TS;
  }
  if (t == 63) wsi[WS_NT] = tx;
}

__global__ void k_scatter(int* __restrict__ wsi) {
  __shared__ int lc[NMODELS];
  __shared__ int lbase[NMODELS];
  int t = threadIdx.x;
  if (t < NMODELS) lc[t] = 0;
  __syncthreads();
  int b = blockIdx.x * 256 + t;
  int e = wsi[WS_SEL + b];
  int r = atomicAdd(&lc[e], 1);
  __syncthreads();
  if (t < NMODELS) {
    int c = lc[t];
    lbase[t] = (c > 0) ? atomicAdd(&wsi[WS_CUR + t], c) : 0;
  }
  __syncthreads();
  wsi[WS_PERM + lbase[e] + r] = b;
}

#define FMA8A(hi, wa, wb, a)                                                 \
  a[0]=fmaf(hi,wa.x,a[0]); a[1]=fmaf(hi,wa.y,a[1]);                          \
  a[2]=fmaf(hi,wa.z,a[2]); a[3]=fmaf(hi,wa.w,a[3]);                          \
  a[4]=fmaf(hi,wb.x,a[4]); a[5]=fmaf(hi,wb.y,a[5]);                          \
  a[6]=fmaf(hi,wb.z,a[6]); a[7]=fmaf(hi,wb.w,a[7]);

#define LOADB8(bias, a)                                                      \
  { const float4* bp = reinterpret_cast<const float4*>((bias) + j0);         \
    float4 u = bp[0], v = bp[1];                                             \
    a[0]=u.x; a[1]=u.y; a[2]=u.z; a[3]=u.w;                                  \
    a[4]=v.x; a[5]=v.y; a[6]=v.z; a[7]=v.w; }

// acc[0..7] = bias[j0..j0+7] + src[s][:] @ W[:, j0..j0+7]
// chunked 8 rows: 16 global float4 loads issued per batch (deep ILP)
__device__ __forceinline__ void mmacc(const float* __restrict__ W,
                                      const float* __restrict__ bias,
                                      const float* src, int s, int j0,
                                      float acc[8]) {
  LOADB8(bias, acc);
  const float* hp = src + s * LSTR;
  for (int i0 = 0; i0 < HID; i0 += 8) {
    float4 h0 = *reinterpret_cast<const float4*>(hp + i0);
    float4 h1 = *reinterpret_cast<const float4*>(hp + i0 + 4);
    float4 w[16];
    #pragma unroll
    for (int k = 0; k < 8; ++k) {
      const float4* wr = reinterpret_cast<const float4*>(W + (size_t)(i0 + k) * HID + j0);
      w[2 * k]     = wr[0];
      w[2 * k + 1] = wr[1];
    }
    float hh[8] = {h0.x, h0.y, h0.z, h0.w, h1.x, h1.y, h1.z, h1.w};
    #pragma unroll
    for (int k = 0; k < 8; ++k) {
      FMA8A(hh[k], w[2 * k], w[2 * k + 1], acc);
    }
  }
}

// two matmuls sharing one pass over src; chunked 4 rows: 16 loads in flight
__device__ __forceinline__ void mmacc2(const float* __restrict__ Wa_,
                                       const float* __restrict__ ba_,
                                       const float* __restrict__ Wb_,
                                       const float* __restrict__ bb_,
                                       const float* src, int s, int j0,
                                       float a1[8], float a2[8]) {
  LOADB8(ba_, a1);
  LOADB8(bb_, a2);
  const float* hp = src + s * LSTR;
  for (int i0 = 0; i0 < HID; i0 += 4) {
    float4 h = *reinterpret_cast<const float4*>(hp + i0);
    float4 wa[8], wb[8];
    #pragma unroll
    for (int k = 0; k < 4; ++k) {
      const float4* wra = reinterpret_cast<const float4*>(Wa_ + (size_t)(i0 + k) * HID + j0);
      const float4* wrb = reinterpret_cast<const float4*>(Wb_ + (size_t)(i0 + k) * HID + j0);
      wa[2 * k]     = wra[0];
      wa[2 * k + 1] = wra[1];
      wb[2 * k]     = wrb[0];
      wb[2 * k + 1] = wrb[1];
    }
    float hh[4] = {h.x, h.y, h.z, h.w};
    #pragma unroll
    for (int k = 0; k < 4; ++k) {
      FMA8A(hh[k], wa[2 * k], wa[2 * k + 1], a1);
      FMA8A(hh[k], wb[2 * k], wb[2 * k + 1], a2);
    }
  }
}

__global__ __launch_bounds__(256, 4) void k_main(
    const float* __restrict__ in,
    const float* __restrict__ W0, const float* __restrict__ b0,
    const float* __restrict__ W1, const float* __restrict__ b1,
    const float* __restrict__ W2, const float* __restrict__ b2,
    const float* __restrict__ W3, const float* __restrict__ b3,
    const float* __restrict__ W4, const float* __restrict__ b4,
    const int* __restrict__ wsi, float* __restrict__ out) {
  __shared__ float Ah[TS * LSTR];
  __shared__ float Bh[TS * LSTR];
  __shared__ float Ch[TS * LSTR];
  __shared__ float w4s[HID * 3], w4e[HID * 3];
  __shared__ int sidx[TS];

  // XCD-chunked swizzle: blocks round-robin to XCDs; give each XCD a
  // contiguous tile range so one expert's weights live in one L2.
  int g = (blockIdx.x % 8) * XCD_CHUNK + blockIdx.x / 8;
  if (g >= wsi[WS_NT]) return;
  int e     = __builtin_amdgcn_readfirstlane(wsi[WS_TILES + g * 3 + 0]);
  int start = __builtin_amdgcn_readfirstlane(wsi[WS_TILES + g * 3 + 1]);
  int cnt   = __builtin_amdgcn_readfirstlane(wsi[WS_TILES + g * 3 + 2]);

  int tid = threadIdx.x;
  int s = tid >> 3, q = tid & 7, j0 = q * 8;
  if (tid < TS) sidx[tid] = (tid < cnt) ? wsi[WS_PERM + start + tid] : -1;
  if (tid < HID * 3) {
    w4s[tid] = W4[tid];
    w4e[tid] = W4[(e + 1) * HID * 3 + tid];
  }
  __syncthreads();
  int idx = sidx[s];

  // ---- L0: x(6) -> Ah ----
  {
    float acc[8];
    LOADB8(b0, acc);
    #pragma unroll
    for (int i = 0; i < 6; ++i) {
      float hi = (idx >= 0) ? in[(size_t)idx * 6 + i] : 0.0f;
      const float4* wr = reinterpret_cast<const float4*>(W0 + i * HID + j0);
      float4 wa = wr[0], wb = wr[1];
      FMA8A(hi, wa, wb, acc);
    }
    #pragma unroll
    for (int k = 0; k < 8; ++k) Ah[s * LSTR + j0 + k] = fmaxf(acc[k], 0.0f);
  }
  __syncthreads();

  // ---- L1: Ah -> Bh (shared W1) ----
  {
    float acc[8];
    mmacc(W1, b1, Ah, s, j0, acc);
    #pragma unroll
    for (int k = 0; k < 8; ++k) Bh[s * LSTR + j0 + k] = fmaxf(acc[k], 0.0f);
  }
  __syncthreads();

  // ---- L2 shared + expert fused (one pass over Bh) ----
  {
    float a1[8], a2[8];
    mmacc2(W2, b2, W2 + (size_t)(e + 1) * HID * HID, b2 + (e + 1) * HID,
           Bh, s, j0, a1, a2);
    #pragma unroll
    for (int k = 0; k < 8; ++k) {
      Ch[s * LSTR + j0 + k] = fmaxf(a1[k], 0.0f);   // h3s
      Ah[s * LSTR + j0 + k] = fmaxf(a2[k], 0.0f);   // h3e (h1 dead)
    }
  }
  __syncthreads();

  const float* W3e = W3 + (size_t)(e + 1) * HID * HID;
  const float* b3e = b3 + (e + 1) * HID;
  float pr[12];
  #pragma unroll
  for (int v = 0; v < 12; ++v) pr[v] = 0.0f;

  // ---- L3 shared + expert fused from h3s (Ch); heads from registers ----
  {
    float a1[8], a2[8];
    mmacc2(W3, b3, W3e, b3e, Ch, s, j0, a1, a2);
    #pragma unroll
    for (int jj = 0; jj < 8; ++jj) {
      int j = j0 + jj;
      float h = fmaxf(a1[jj], 0.0f);                // h4ss -> lod0 (w4s), lod1 (w4e)
      pr[0] = fmaf(h, w4s[j * 3 + 0], pr[0]);
      pr[1] = fmaf(h, w4s[j * 3 + 1], pr[1]);
      pr[2] = fmaf(h, w4s[j * 3 + 2], pr[2]);
      pr[3] = fmaf(h, w4e[j * 3 + 0], pr[3]);
      pr[4] = fmaf(h, w4e[j * 3 + 1], pr[4]);
      pr[5] = fmaf(h, w4e[j * 3 + 2], pr[5]);
      float g2 = fmaxf(a2[jj], 0.0f);               // h4se -> lod2 (w4e)
      pr[6] = fmaf(g2, w4e[j * 3 + 0], pr[6]);
      pr[7] = fmaf(g2, w4e[j * 3 + 1], pr[7]);
      pr[8] = fmaf(g2, w4e[j * 3 + 2], pr[8]);
    }
  }

  // ---- expert L3 from h3e (Ah); head lod3 ----
  {
    float acc[8];
    mmacc(W3e, b3e, Ah, s, j0, acc);
    #pragma unroll
    for (int jj = 0; jj < 8; ++jj) {
      int j = j0 + jj;
      float h = fmaxf(acc[jj], 0.0f);               // h4ee -> lod3 (w4e)
      pr[9]  = fmaf(h, w4e[j * 3 + 0], pr[9]);
      pr[10] = fmaf(h, w4e[j * 3 + 1], pr[10]);
      pr[11] = fmaf(h, w4e[j * 3 + 2], pr[11]);
    }
  }

  // reduce partials across the 8 threads of each sample
  #pragma unroll
  for (int v = 0; v < 12; ++v) {
    pr[v] += __shfl_xor(pr[v], 1);
    pr[v] += __shfl_xor(pr[v], 2);
    pr[v] += __shfl_xor(pr[v], 4);
  }
  if (q == 0 && idx >= 0) {
    const float* b4e = b4 + (e + 1) * 3;
    pr[0] += b4[0];  pr[1] += b4[1];  pr[2] += b4[2];
    pr[3] += b4e[0]; pr[4] += b4e[1]; pr[5] += b4e[2];
    pr[6] += b4e[0]; pr[7] += b4e[1]; pr[8] += b4e[2];
    pr[9] += b4e[0]; pr[10] += b4e[1]; pr[11] += b4e[2];
    float4* op = reinterpret_cast<float4*>(out + (size_t)idx * 12);
    op[0] = make_float4(pr[0], pr[1], pr[2], pr[3]);
    op[1] = make_float4(pr[4], pr[5], pr[6], pr[7]);
    op[2] = make_float4(pr[8], pr[9], pr[10], pr[11]);
  }
}

extern "C" void kernel_launch(void* const* d_in, const int* in_sizes, int n_in,
                              void* d_out, int out_size, void* d_ws, size_t ws_size,
                              hipStream_t stream) {
  const float* in = (const float*)d_in[0];
  const float* W0 = (const float*)d_in[1];
  const float* b0 = (const float*)d_in[2];
  const float* W1 = (const float*)d_in[3];
  const float* b1 = (const float*)d_in[4];
  const float* W2 = (const float*)d_in[5];
  const float* b2 = (const float*)d_in[6];
  const float* W3 = (const float*)d_in[7];
  const float* b3 = (const float*)d_in[8];
  const float* W4 = (const float*)d_in[9];
  const float* b4 = (const float*)d_in[10];
  float* out = (float*)d_out;
  int* wsi = (int*)d_ws;

  hipLaunchKernelGGL(k_init,    dim3(1),    dim3(64),  0, stream, wsi);
  hipLaunchKernelGGL(k_route,   dim3(128),  dim3(256), 0, stream, in, out, wsi);
  hipLaunchKernelGGL(k_prefix,  dim3(1),    dim3(64),  0, stream, wsi);
  hipLaunchKernelGGL(k_scatter, dim3(128),  dim3(256), 0, stream, wsi);
  hipLaunchKernelGGL(k_main,    dim3(MAX_TILES), dim3(256), 0, stream,
                     in, W0, b0, W1, b1, W2, b2, W3, b3, W4, b4, wsi, out);
}

// Round 10
// 147.190 us; speedup vs baseline: 1.4387x; 1.4387x over previous
//
#include <hip/hip_runtime.h>
#include <math.h>

#define NMODELS 64
#define HID     64
#define TILE    128         // samples per block (one chunk, 2 per thread)
#define LSTR    68          // act row stride: 272B, 16B-aligned rows

// workspace layout (int32 indices)
#define WS_NT    0
#define WS_HIST  16
#define WS_CUR   96
#define WS_TILES 192        // 3 ints per tile
#define MAX_TILES 320       // 32768/128 + 64 = 8 * 40
#define XCHUNK   40
#define WS_SEL   4096
#define WS_PERM  36864

// output layout (float32 indices)
#define OUT_SEL  393216
#define OUT_LOG  425984
#define OUT_PROB 2523136

__global__ void k_init(int* __restrict__ wsi) {
  if (threadIdx.x < NMODELS) wsi[WS_HIST + threadIdx.x] = 0;
}

// routing + constant fills (logits=1, probs=1/64) in one pass
__global__ void k_route(const float* __restrict__ in, float* __restrict__ out,
                        int* __restrict__ wsi) {
  __shared__ int lh[NMODELS];
  int t = threadIdx.x;
  if (t < NMODELS) lh[t] = 0;
  __syncthreads();
  int b = blockIdx.x * 256 + t;          // 0..32767

  {
    float4 one = make_float4(1.f, 1.f, 1.f, 1.f);
    float4 pr  = make_float4(0.015625f, 0.015625f, 0.015625f, 0.015625f);
    float4* lg = reinterpret_cast<float4*>(out + OUT_LOG);
    float4* pb = reinterpret_cast<float4*>(out + OUT_PROB);
    #pragma unroll
    for (int k = 0; k < 16; ++k) {
      lg[k * 32768 + b] = one;
      pb[k * 32768 + b] = pr;
    }
  }

  float x = in[b * 6 + 0];
  float z = in[b * 6 + 2];
  const float TWO_PI = 6.283185307179586476925286766559f;
  // f64 atan2 rounded to f32 ~= correctly-rounded f32 atan2 (matches numpy);
  // remaining chain is IEEE-exact f32, bit-identical to the reference.
  float ang = (float)atan2((double)z, (double)x);
  float tt  = ang + TWO_PI;
  float m   = fmodf(tt, TWO_PI);
  float a   = m / TWO_PI * 64.0f;
  int e = (int)floorf(a);
  e = e < 0 ? 0 : (e > 63 ? 63 : e);
  out[OUT_SEL + b] = (float)e;
  wsi[WS_SEL + b]  = e;
  atomicAdd(&lh[e], 1);
  __syncthreads();
  if (t < NMODELS && lh[t] > 0) atomicAdd(&wsi[WS_HIST + t], lh[t]);
}

__global__ void k_prefix(int* __restrict__ wsi) {  // 1 block, 64 threads (one wave)
  int t = threadIdx.x;      // t = expert id
  int c = wsi[WS_HIST + t];
  int x = c;
  #pragma unroll
  for (int d = 1; d < 64; d <<= 1) {
    int y = __shfl_up(x, d, 64);
    if (t >= d) x += y;
  }
  int off = x - c;                 // exclusive prefix of counts
  wsi[WS_CUR + t] = off;           // scatter cursor starts at segment base
  int ntile_me = (c + TILE - 1) >> 7;
  int tx = ntile_me;
  #pragma unroll
  for (int d = 1; d < 64; d <<= 1) {
    int y = __shfl_up(tx, d, 64);
    if (t >= d) tx += y;
  }
  int tbase = tx - ntile_me;
  for (int k = 0; k < ntile_me; ++k) {
    int rem = c - k * TILE;
    wsi[WS_TILES + (tbase + k) * 3 + 0] = t;
    wsi[WS_TILES + (tbase + k) * 3 + 1] = off + k * TILE;
    wsi[WS_TILES + (tbase + k) * 3 + 2] = rem < TILE ? rem : TILE;
  }
  if (t == 63) wsi[WS_NT] = tx;
}

__global__ void k_scatter(int* __restrict__ wsi) {
  __shared__ int lc[NMODELS];
  __shared__ int lbase[NMODELS];
  int t = threadIdx.x;
  if (t < NMODELS) lc[t] = 0;
  __syncthreads();
  int b = blockIdx.x * 256 + t;
  int e = wsi[WS_SEL + b];
  int r = atomicAdd(&lc[e], 1);
  __syncthreads();
  if (t < NMODELS) {
    int c = lc[t];
    lbase[t] = (c > 0) ? atomicAdd(&wsi[WS_CUR + t], c) : 0;
  }
  __syncthreads();
  wsi[WS_PERM + lbase[e] + r] = b;
}

#define FMA8A(hi, wa, wb, a)                                                 \
  a[0]=fmaf(hi,wa.x,a[0]); a[1]=fmaf(hi,wa.y,a[1]);                          \
  a[2]=fmaf(hi,wa.z,a[2]); a[3]=fmaf(hi,wa.w,a[3]);                          \
  a[4]=fmaf(hi,wb.x,a[4]); a[5]=fmaf(hi,wb.y,a[5]);                          \
  a[6]=fmaf(hi,wb.z,a[6]); a[7]=fmaf(hi,wb.w,a[7]);

// one matrix (LDS), two samples (s, s+64): weights read once, used twice
__device__ __forceinline__ void mm1_dual(const float* __restrict__ W,
                                         const float* __restrict__ bias,
                                         const float* __restrict__ A,
                                         int s, int j0,
                                         float a0[8], float a1[8]) {
  #pragma unroll
  for (int k = 0; k < 8; ++k) { float bv = bias[j0 + k]; a0[k] = bv; a1[k] = bv; }
  const float* h0p = A + s * LSTR;
  const float* h1p = A + (s + 64) * LSTR;
  #pragma unroll 4
  for (int i0 = 0; i0 < HID; i0 += 4) {
    float4 h0 = *reinterpret_cast<const float4*>(h0p + i0);
    float4 h1 = *reinterpret_cast<const float4*>(h1p + i0);
    float hh0[4] = {h0.x, h0.y, h0.z, h0.w};
    float hh1[4] = {h1.x, h1.y, h1.z, h1.w};
    #pragma unroll
    for (int k = 0; k < 4; ++k) {
      const float4* wr = reinterpret_cast<const float4*>(W + (i0 + k) * HID + j0);
      float4 wa = wr[0], wb = wr[1];
      FMA8A(hh0[k], wa, wb, a0);
      FMA8A(hh1[k], wa, wb, a1);
    }
  }
}

// two matrices (LDS), two samples: one h-read feeds 4 accumulators
__device__ __forceinline__ void mm2_dual(const float* __restrict__ Wa_,
                                         const float* __restrict__ ba_,
                                         const float* __restrict__ Wb_,
                                         const float* __restrict__ bb_,
                                         const float* __restrict__ A,
                                         int s, int j0,
                                         float a0[8], float b0a[8],
                                         float a1[8], float b1a[8]) {
  #pragma unroll
  for (int k = 0; k < 8; ++k) {
    float bva = ba_[j0 + k], bvb = bb_[j0 + k];
    a0[k] = bva; a1[k] = bva; b0a[k] = bvb; b1a[k] = bvb;
  }
  const float* h0p = A + s * LSTR;
  const float* h1p = A + (s + 64) * LSTR;
  #pragma unroll 2
  for (int i0 = 0; i0 < HID; i0 += 4) {
    float4 h0 = *reinterpret_cast<const float4*>(h0p + i0);
    float4 h1 = *reinterpret_cast<const float4*>(h1p + i0);
    float hh0[4] = {h0.x, h0.y, h0.z, h0.w};
    float hh1[4] = {h1.x, h1.y, h1.z, h1.w};
    #pragma unroll
    for (int k = 0; k < 4; ++k) {
      const float4* wra = reinterpret_cast<const float4*>(Wa_ + (i0 + k) * HID + j0);
      const float4* wrb = reinterpret_cast<const float4*>(Wb_ + (i0 + k) * HID + j0);
      float4 wa = wra[0], wb = wra[1];
      float4 wc = wrb[0], wd = wrb[1];
      FMA8A(hh0[k], wa, wb, a0);
      FMA8A(hh0[k], wc, wd, b0a);
      FMA8A(hh1[k], wa, wb, a1);
      FMA8A(hh1[k], wc, wd, b1a);
    }
  }
}

__global__ __launch_bounds__(512, 1) void k_main(
    const float* __restrict__ in,
    const float* __restrict__ W0, const float* __restrict__ b0,
    const float* __restrict__ W1, const float* __restrict__ b1,
    const float* __restrict__ W2, const float* __restrict__ b2,
    const float* __restrict__ W3, const float* __restrict__ b3,
    const float* __restrict__ W4, const float* __restrict__ b4,
    const int* __restrict__ wsi, float* __restrict__ out) {
  __shared__ __align__(16) float WL[5 * 4096];     // W1,W2s,W2e,W3s,W3e (80 KB)
  __shared__ __align__(16) float Ah[TILE * LSTR];  // 34.8 KB
  __shared__ __align__(16) float Bh[TILE * LSTR];  // 34.8 KB
  __shared__ __align__(16) float bL[704];          // b1,b2s,b2e,b3s,b3e,w4s,w4e
  __shared__ int sidx[TILE];

  int g = (blockIdx.x % 8) * XCHUNK + blockIdx.x / 8;   // XCD-chunked swizzle
  if (g >= wsi[WS_NT]) return;
  int e     = __builtin_amdgcn_readfirstlane(wsi[WS_TILES + g * 3 + 0]);
  int start = __builtin_amdgcn_readfirstlane(wsi[WS_TILES + g * 3 + 1]);
  int cnt   = __builtin_amdgcn_readfirstlane(wsi[WS_TILES + g * 3 + 2]);

  int tid = threadIdx.x;

  // ---- stage weights once: 5 x 4096 floats, 1024 float4 each ----
  {
    const float* gs[5] = {W1, W2, W2 + (size_t)(e + 1) * 4096,
                          W3, W3 + (size_t)(e + 1) * 4096};
    #pragma unroll
    for (int m = 0; m < 5; ++m) {
      const float4* s4 = reinterpret_cast<const float4*>(gs[m]);
      float4* d4 = reinterpret_cast<float4*>(WL + m * 4096);
      d4[tid]       = s4[tid];
      d4[tid + 512] = s4[tid + 512];
    }
  }
  if (tid < 64) {
    bL[tid]       = b1[tid];
    bL[64 + tid]  = b2[tid];
    bL[128 + tid] = b2[(e + 1) * 64 + tid];
    bL[192 + tid] = b3[tid];
    bL[256 + tid] = b3[(e + 1) * 64 + tid];
  }
  if (tid < 192) {
    bL[320 + tid] = W4[tid];
    bL[512 + tid] = W4[(size_t)(e + 1) * 192 + tid];
  }
  if (tid < TILE) sidx[tid] = (tid < cnt) ? wsi[WS_PERM + start + tid] : -1;
  __syncthreads();

  int s = tid >> 3, q = tid & 7, j0 = q * 8;
  int idx0 = sidx[s], idx1 = sidx[s + 64];

  // ---- L0: x(6) -> Ah (W0 tiny, from global/L1) ----
  {
    float a0[8], a1[8];
    #pragma unroll
    for (int k = 0; k < 8; ++k) { float bv = b0[j0 + k]; a0[k] = bv; a1[k] = bv; }
    #pragma unroll
    for (int i = 0; i < 6; ++i) {
      const float4* wr = reinterpret_cast<const float4*>(W0 + i * HID + j0);
      float4 wa = wr[0], wb = wr[1];
      float h0 = (idx0 >= 0) ? in[(size_t)idx0 * 6 + i] : 0.0f;
      float h1 = (idx1 >= 0) ? in[(size_t)idx1 * 6 + i] : 0.0f;
      FMA8A(h0, wa, wb, a0);
      FMA8A(h1, wa, wb, a1);
    }
    #pragma unroll
    for (int k = 0; k < 8; ++k) {
      Ah[s * LSTR + j0 + k]        = fmaxf(a0[k], 0.0f);
      Ah[(s + 64) * LSTR + j0 + k] = fmaxf(a1[k], 0.0f);
    }
  }
  __syncthreads();

  // ---- L1: Ah -> Bh ----
  {
    float a0[8], a1[8];
    mm1_dual(WL, bL, Ah, s, j0, a0, a1);
    #pragma unroll
    for (int k = 0; k < 8; ++k) {
      Bh[s * LSTR + j0 + k]        = fmaxf(a0[k], 0.0f);
      Bh[(s + 64) * LSTR + j0 + k] = fmaxf(a1[k], 0.0f);
    }
  }
  __syncthreads();

  // ---- L2 shared+expert from Bh -> regs; then Ah:=h3s, Bh:=h3e ----
  {
    float s0[8], e0[8], s1[8], e1[8];
    mm2_dual(WL + 4096, bL + 64, WL + 8192, bL + 128, Bh, s, j0, s0, e0, s1, e1);
    __syncthreads();   // all Bh reads complete before overwrite
    #pragma unroll
    for (int k = 0; k < 8; ++k) {
      Ah[s * LSTR + j0 + k]        = fmaxf(s0[k], 0.0f);
      Ah[(s + 64) * LSTR + j0 + k] = fmaxf(s1[k], 0.0f);
      Bh[s * LSTR + j0 + k]        = fmaxf(e0[k], 0.0f);
      Bh[(s + 64) * LSTR + j0 + k] = fmaxf(e1[k], 0.0f);
    }
  }
  __syncthreads();

  float pr0[12], pr1[12];
  #pragma unroll
  for (int v = 0; v < 12; ++v) { pr0[v] = 0.0f; pr1[v] = 0.0f; }
  const float* w4s = bL + 320;
  const float* w4e = bL + 512;

  // ---- L3 shared+expert from h3s (Ah); heads in registers ----
  {
    float x0[8], y0[8], x1[8], y1[8];
    mm2_dual(WL + 12288, bL + 192, WL + 16384, bL + 256, Ah, s, j0, x0, y0, x1, y1);
    #pragma unroll
    for (int jj = 0; jj < 8; ++jj) {
      int j = j0 + jj;
      float hss0 = fmaxf(x0[jj], 0.0f);          // lod0 (w4s), lod1 (w4e)
      float hss1 = fmaxf(x1[jj], 0.0f);
      float hse0 = fmaxf(y0[jj], 0.0f);          // lod2 (w4e)
      float hse1 = fmaxf(y1[jj], 0.0f);
      #pragma unroll
      for (int c = 0; c < 3; ++c) {
        float ws_ = w4s[j * 3 + c], we_ = w4e[j * 3 + c];
        pr0[0 + c] = fmaf(hss0, ws_, pr0[0 + c]);
        pr0[3 + c] = fmaf(hss0, we_, pr0[3 + c]);
        pr0[6 + c] = fmaf(hse0, we_, pr0[6 + c]);
        pr1[0 + c] = fmaf(hss1, ws_, pr1[0 + c]);
        pr1[3 + c] = fmaf(hss1, we_, pr1[3 + c]);
        pr1[6 + c] = fmaf(hse1, we_, pr1[6 + c]);
      }
    }
  }
  // ---- expert L3 from h3e (Bh); head lod3 ----
  {
    float x0[8], x1[8];
    mm1_dual(WL + 16384, bL + 256, Bh, s, j0, x0, x1);
    #pragma unroll
    for (int jj = 0; jj < 8; ++jj) {
      int j = j0 + jj;
      float h0 = fmaxf(x0[jj], 0.0f);
      float h1 = fmaxf(x1[jj], 0.0f);
      #pragma unroll
      for (int c = 0; c < 3; ++c) {
        float we_ = w4e[j * 3 + c];
        pr0[9 + c] = fmaf(h0, we_, pr0[9 + c]);
        pr1[9 + c] = fmaf(h1, we_, pr1[9 + c]);
      }
    }
  }

  // reduce partials across the 8 threads of each sample
  #pragma unroll
  for (int v = 0; v < 12; ++v) {
    pr0[v] += __shfl_xor(pr0[v], 1);
    pr0[v] += __shfl_xor(pr0[v], 2);
    pr0[v] += __shfl_xor(pr0[v], 4);
    pr1[v] += __shfl_xor(pr1[v], 1);
    pr1[v] += __shfl_xor(pr1[v], 2);
    pr1[v] += __shfl_xor(pr1[v], 4);
  }
  if (q == 0) {
    float c0 = b4[0], c1 = b4[1], c2 = b4[2];
    float e0 = b4[(e + 1) * 3 + 0], e1 = b4[(e + 1) * 3 + 1], e2 = b4[(e + 1) * 3 + 2];
    if (idx0 >= 0) {
      float4* op = reinterpret_cast<float4*>(out + (size_t)idx0 * 12);
      op[0] = make_float4(pr0[0] + c0, pr0[1] + c1, pr0[2] + c2, pr0[3] + e0);
      op[1] = make_float4(pr0[4] + e1, pr0[5] + e2, pr0[6] + e0, pr0[7] + e1);
      op[2] = make_float4(pr0[8] + e2, pr0[9] + e0, pr0[10] + e1, pr0[11] + e2);
    }
    if (idx1 >= 0) {
      float4* op = reinterpret_cast<float4*>(out + (size_t)idx1 * 12);
      op[0] = make_float4(pr1[0] + c0, pr1[1] + c1, pr1[2] + c2, pr1[3] + e0);
      op[1] = make_float4(pr1[4] + e1, pr1[5] + e2, pr1[6] + e0, pr1[7] + e1);
      op[2] = make_float4(pr1[8] + e2, pr1[9] + e0, pr1[10] + e1, pr1[11] + e2);
    }
  }
}

extern "C" void kernel_launch(void* const* d_in, const int* in_sizes, int n_in,
                              void* d_out, int out_size, void* d_ws, size_t ws_size,
                              hipStream_t stream) {
  const float* in = (const float*)d_in[0];
  const float* W0 = (const float*)d_in[1];
  const float* b0 = (const float*)d_in[2];
  const float* W1 = (const float*)d_in[3];
  const float* b1 = (const float*)d_in[4];
  const float* W2 = (const float*)d_in[5];
  const float* b2 = (const float*)d_in[6];
  const float* W3 = (const float*)d_in[7];
  const float* b3 = (const float*)d_in[8];
  const float* W4 = (const float*)d_in[9];
  const float* b4 = (const float*)d_in[10];
  float* out = (float*)d_out;
  int* wsi = (int*)d_ws;

  hipLaunchKernelGGL(k_init,    dim3(1),    dim3(64),  0, stream, wsi);
  hipLaunchKernelGGL(k_route,   dim3(128),  dim3(256), 0, stream, in, out, wsi);
  hipLaunchKernelGGL(k_prefix,  dim3(1),    dim3(64),  0, stream, wsi);
  hipLaunchKernelGGL(k_scatter, dim3(128),  dim3(256), 0, stream, wsi);
  hipLaunchKernelGGL(k_main,    dim3(MAX_TILES), dim3(512), 0, stream,
                     in, W0, b0, W1, b1, W2, b2, W3, b3, W4, b4, wsi, out);
}